// Round 1
// baseline (459.074 us; speedup 1.0000x reference)
//
#include <hip/hip_runtime.h>

typedef unsigned int u32;
typedef unsigned short u16;
typedef float f32x4 __attribute__((ext_vector_type(4)));
typedef u32 u32x4 __attribute__((ext_vector_type(4)));

#define DEVINL static __device__ __forceinline__

#if defined(__has_builtin)
#if __has_builtin(__builtin_amdgcn_exp2f)
#define EXP2F(x) __builtin_amdgcn_exp2f(x)
#else
#define EXP2F(x) exp2f(x)
#endif
#else
#define EXP2F(x) exp2f(x)
#endif

#define LOG2E 1.44269504088896340736f

DEVINL u16 f2bf(float f) {
  u32 u = __builtin_bit_cast(u32, f);
  u32 r = u + 0x7FFFu + ((u >> 16) & 1u);
  return (u16)(r >> 16);
}

DEVINL void mfma_b16(f32x4& c, u32x4 a, u32x4 b) {
  asm volatile("v_mfma_f32_16x16x32_bf16 %0, %1, %2, %0" : "+v"(c) : "v"(a), "v"(b));
}
DEVINL void mfma_fence() { asm volatile("s_nop 7\n\ts_nop 7"); }

// ---------------------------------------------------------------------------
// prep: transpose weights to [N][K] bf16, concat qkv bias
// ---------------------------------------------------------------------------
__global__ void prep_kernel(const float* __restrict__ Wq, const float* __restrict__ Wk,
                            const float* __restrict__ Wv, const float* __restrict__ Wo,
                            const float* __restrict__ bq, const float* __restrict__ bk,
                            const float* __restrict__ bv,
                            u16* __restrict__ WqkvT, u16* __restrict__ WoT,
                            float* __restrict__ biasQKV) {
  int gid = blockIdx.x * blockDim.x + threadIdx.x;
  int stride = gridDim.x * blockDim.x;
  for (int i = gid; i < 1536 * 256; i += stride) {
    int cc = i >> 8, k = i & 255;
    const float* W = cc < 512 ? Wq : (cc < 1024 ? Wk : Wv);
    WqkvT[i] = f2bf(W[k * 512 + (cc & 511)]);
  }
  for (int i = gid; i < 512 * 512; i += stride) {
    int cc = i >> 9, k = i & 511;
    WoT[i] = f2bf(Wo[k * 512 + cc]);
  }
  for (int i = gid; i < 1536; i += stride)
    biasQKV[i] = i < 512 ? bq[i] : (i < 1024 ? bk[i - 512] : bv[i - 1024]);
}

// ---------------------------------------------------------------------------
// topk: one wave per row; exact f32 top-32 with jax tie-break (lower index),
// outputs index-sorted lists with weights pre-scaled by tau/rowsum.
// ---------------------------------------------------------------------------
__global__ __launch_bounds__(256) void topk_kernel(const float* __restrict__ sim,
                                                   const float* __restrict__ tau_raw,
                                                   int* __restrict__ idx_out,
                                                   float* __restrict__ w_out) {
  const int tid = threadIdx.x, lane = tid & 63, w = tid >> 6;
  const int row = blockIdx.x * 4 + w;
  const int b = row >> 11, n = row & 2047;
  const float* src = sim + ((size_t)b * 2048 + n) * 2048;

  float vals[32];
#pragma unroll
  for (int q = 0; q < 8; q++) {
    f32x4 v = *(const f32x4*)(src + q * 256 + lane * 4);
#pragma unroll
    for (int j = 0; j < 4; j++) {
      int m = (q << 8) + lane * 4 + j;
      float x = fmaxf(v[j], 0.f);
      vals[q * 4 + j] = (m == n) ? -1e30f : x;
    }
  }
  u32 used = 0;
  float bv;
  int bm;
  auto rescan = [&]() {
    bv = -2e30f;
    bm = 0x7fffffff;
#pragma unroll
    for (int e = 0; e < 32; e++) {
      float v = ((used >> e) & 1u) ? -2e30f : vals[e];
      int m = ((e >> 2) << 8) + lane * 4 + (e & 3);
      bool take = (v > bv) || (v == bv && m < bm);
      bv = take ? v : bv;
      bm = take ? m : bm;
    }
  };
  rescan();
  int myidx = 0;
  float myval = 0.f;
  for (int it = 0; it < 32; it++) {
    float cv = bv;
    int cm = bm;
#pragma unroll
    for (int off = 1; off < 64; off <<= 1) {
      float ov = __shfl_xor(cv, off, 64);
      int om = __shfl_xor(cm, off, 64);
      bool take = (ov > cv) || (ov == cv && om < cm);
      cv = take ? ov : cv;
      cm = take ? om : cm;
    }
    if (lane == it) { myidx = cm; myval = cv; }
    if (cm == bm) {  // this lane owns the winner (m encodes lane -> unique)
      used |= 1u << (((cm >> 8) << 2) | (cm & 3));
      rescan();
    }
  }
  float sv = (lane < 32) ? myval : 0.f;
#pragma unroll
  for (int off = 1; off < 64; off <<= 1) sv += __shfl_xor(sv, off, 64);
  float tau = log1pf(__expf(tau_raw[0]));  // softplus
  float wv = tau * myval / fmaxf(sv, 1e-8f);
  int rank = 0;
  for (int j2 = 0; j2 < 32; j2++) {
    int oj = __shfl(myidx, j2, 64);
    rank += (oj < myidx) ? 1 : 0;
  }
  if (lane < 32) {
    idx_out[(size_t)row * 32 + rank] = myidx;
    w_out[(size_t)row * 32 + rank] = wv;
  }
}

// ---------------------------------------------------------------------------
// NT GEMM: A [M][K] f32, Bt [N][K] bf16, 128x128 tile, BK=32, 4 waves.
// MODE 0: scatter bf16 to Q/K/V head-split buffers. MODE 1: f32 out [M][N].
// ---------------------------------------------------------------------------
template <int MODE>
__global__ __launch_bounds__(256) void gemm_nt(const float* __restrict__ A,
                                               const u16* __restrict__ Bt,
                                               const float* __restrict__ bias,
                                               u16* __restrict__ outQ, u16* __restrict__ outK,
                                               u16* __restrict__ outV, float* __restrict__ outF,
                                               int M, int N, int K) {
  __shared__ __align__(16) u16 As[128 * 32];
  __shared__ __align__(16) u16 Bs[128 * 32];

  const int tid = threadIdx.x;
  const int lane = tid & 63;
  const int w = tid >> 6;
  const int g = lane >> 4, c = lane & 15;
  const int wr = (w >> 1) * 64, wc = (w & 1) * 64;
  const int m0 = blockIdx.y * 128, n0 = blockIdx.x * 128;

  f32x4 acc[4][4];
#pragma unroll
  for (int i = 0; i < 4; i++)
#pragma unroll
    for (int j = 0; j < 4; j++) acc[i][j] = f32x4{0.f, 0.f, 0.f, 0.f};

  const int srow = tid >> 1;
  const int shalf = tid & 1;
  const float* Arow = A + (size_t)(m0 + srow) * K + shalf * 16;
  const u16* Brow = Bt + (size_t)(n0 + srow) * K + shalf * 16;
  char* asbase = (char*)As;
  char* bsbase = (char*)Bs;
  const u32 swz = (u32)((srow & 7) << 4);
  const u32 wb0 = (u32)(srow * 64 + shalf * 32);

  for (int kt = 0; kt < K; kt += 32) {
    __syncthreads();
    {
      f32x4 v0 = *(const f32x4*)(Arow + kt);
      f32x4 v1 = *(const f32x4*)(Arow + kt + 4);
      f32x4 v2 = *(const f32x4*)(Arow + kt + 8);
      f32x4 v3 = *(const f32x4*)(Arow + kt + 12);
      u32x4 pa, pb;
      pa[0] = (u32)f2bf(v0[0]) | ((u32)f2bf(v0[1]) << 16);
      pa[1] = (u32)f2bf(v0[2]) | ((u32)f2bf(v0[3]) << 16);
      pa[2] = (u32)f2bf(v1[0]) | ((u32)f2bf(v1[1]) << 16);
      pa[3] = (u32)f2bf(v1[2]) | ((u32)f2bf(v1[3]) << 16);
      pb[0] = (u32)f2bf(v2[0]) | ((u32)f2bf(v2[1]) << 16);
      pb[1] = (u32)f2bf(v2[2]) | ((u32)f2bf(v2[3]) << 16);
      pb[2] = (u32)f2bf(v3[0]) | ((u32)f2bf(v3[1]) << 16);
      pb[3] = (u32)f2bf(v3[2]) | ((u32)f2bf(v3[3]) << 16);
      *(u32x4*)(asbase + ((wb0 + 0) ^ swz)) = pa;
      *(u32x4*)(asbase + ((wb0 + 16) ^ swz)) = pb;
      u32x4 b0 = *(const u32x4*)(Brow + kt);
      u32x4 b1 = *(const u32x4*)(Brow + kt + 8);
      *(u32x4*)(bsbase + ((wb0 + 0) ^ swz)) = b0;
      *(u32x4*)(bsbase + ((wb0 + 16) ^ swz)) = b1;
    }
    __syncthreads();
    u32x4 af[4], bfr[4];
#pragma unroll
    for (int fr = 0; fr < 4; fr++) {
      int row = wr + fr * 16 + c;
      af[fr] = *(const u32x4*)(asbase + ((u32)(row * 64 + g * 16) ^ ((u32)((row & 7) << 4))));
    }
#pragma unroll
    for (int fc = 0; fc < 4; fc++) {
      int row = wc + fc * 16 + c;
      bfr[fc] = *(const u32x4*)(bsbase + ((u32)(row * 64 + g * 16) ^ ((u32)((row & 7) << 4))));
    }
#pragma unroll
    for (int fr = 0; fr < 4; fr++)
#pragma unroll
      for (int fc = 0; fc < 4; fc++) mfma_b16(acc[fr][fc], af[fr], bfr[fc]);
  }
  mfma_fence();
#pragma unroll
  for (int fc = 0; fc < 4; fc++) {
    int gcol = n0 + wc + fc * 16 + c;
    float bvv = bias[gcol];
#pragma unroll
    for (int fr = 0; fr < 4; fr++) {
#pragma unroll
      for (int r = 0; r < 4; r++) {
        int grow = m0 + wr + fr * 16 + 4 * g + r;
        float v = acc[fr][fc][r] + bvv;
        if (MODE == 0) {
          int sel = gcol >> 9, c9 = gcol & 511;
          int hh = c9 >> 6, dd = c9 & 63;
          int bb = grow >> 11, nn = grow & 2047;
          size_t off2 = ((size_t)(bb * 8 + hh) * 2048 + nn) * 64 + dd;
          u16* dst = sel == 0 ? outQ : (sel == 1 ? outK : outV);
          dst[off2] = f2bf(v);
        } else {
          outF[(size_t)grow * N + gcol] = v;
        }
      }
    }
  }
}

// ---------------------------------------------------------------------------
// transpose V: [BH][N][64] -> [BH][64][N] (bf16)
// ---------------------------------------------------------------------------
__global__ __launch_bounds__(256) void transpose_v(const u16* __restrict__ Vb,
                                                   u16* __restrict__ Vt) {
  __shared__ __align__(16) u16 T[64 * 72];
  const int nt = blockIdx.x, bh = blockIdx.y;
  const int tid = threadIdx.x;
  const int rr = tid >> 2, q = tid & 3;
  {
    const u16* src = Vb + ((size_t)bh * 2048 + nt * 64 + rr) * 64 + q * 16;
    u32x4 a = *(const u32x4*)src;
    u32x4 b = *(const u32x4*)(src + 8);
    *(u32x4*)(&T[rr * 72 + q * 16]) = a;
    *(u32x4*)(&T[rr * 72 + q * 16 + 8]) = b;
  }
  __syncthreads();
  {
    union { u16 s[16]; u32x4 v[2]; } ou;
#pragma unroll
    for (int e = 0; e < 16; e++) ou.s[e] = T[(q * 16 + e) * 72 + rr];
    u16* dst = Vt + ((size_t)bh * 64 + rr) * 2048 + nt * 64 + q * 16;
    *(u32x4*)dst = ou.v[0];
    *(u32x4*)(dst + 8) = ou.v[1];
  }
}

// ---------------------------------------------------------------------------
// flash attention with sparse additive bias. grid (qt=32, bh=32), 4 waves.
// Q/K row-major [BH][N][64] bf16, V transposed [BH][64][N] bf16.
// ---------------------------------------------------------------------------
__global__ __launch_bounds__(256) void attn_kernel(const u16* __restrict__ Qb,
                                                   const u16* __restrict__ Kb,
                                                   const u16* __restrict__ Vt,
                                                   const int* __restrict__ tidx,
                                                   const float* __restrict__ tw,
                                                   float* __restrict__ attnout) {
  __shared__ __align__(16) u16 Ks[64 * 64];
  __shared__ __align__(16) u16 Vs[64 * 64];
  __shared__ __align__(16) u16 Ps[4][16 * 64];
  __shared__ int idxs[64 * 32];
  __shared__ float wss[64 * 32];

  const int qt = blockIdx.x, bh = blockIdx.y;
  const int b = bh >> 3, h = bh & 7;
  const int tid = threadIdx.x, lane = tid & 63, w = tid >> 6;
  const int g = lane >> 4, c = lane & 15;
  const int qbase = qt * 64;

  for (int i = tid; i < 2048; i += 256) {
    size_t srcoff = ((size_t)b * 2048 + qbase) * 32 + i;
    idxs[i] = tidx[srcoff];
    wss[i] = tw[srcoff];
  }

  const u16* qptr = Qb + ((size_t)bh * 2048 + qbase + w * 16 + c) * 64 + g * 8;
  u32x4 aq0 = *(const u32x4*)qptr;
  u32x4 aq1 = *(const u32x4*)(qptr + 32);

  float mrow[4], ssum[4];
  f32x4 o[4];
  int ptr4[4];
#pragma unroll
  for (int r = 0; r < 4; r++) {
    mrow[r] = -1e30f;
    ssum[r] = 0.f;
    ptr4[r] = 0;
    o[r] = f32x4{0.f, 0.f, 0.f, 0.f};
  }

  const int sr = tid >> 2, sq = tid & 3;
  const u16* ksrc = Kb + ((size_t)bh * 2048 + sr) * 64 + sq * 16;
  const u16* vsrc = Vt + ((size_t)bh * 64 + sr) * 2048 + sq * 16;
  char* ksb = (char*)Ks;
  char* vsb = (char*)Vs;
  char* pwb = (char*)&Ps[w][0];
  const u32 sswz = (u32)((sr & 7) << 4);
  const u32 sb0 = (u32)(sr * 128 + sq * 32);

  for (int jt = 0; jt < 2048; jt += 64) {
    __syncthreads();
    {
      u32x4 k0 = *(const u32x4*)(ksrc + (size_t)jt * 64);
      u32x4 k1 = *(const u32x4*)(ksrc + (size_t)jt * 64 + 8);
      u32x4 v0 = *(const u32x4*)(vsrc + jt);
      u32x4 v1 = *(const u32x4*)(vsrc + jt + 8);
      *(u32x4*)(ksb + ((sb0 + 0) ^ sswz)) = k0;
      *(u32x4*)(ksb + ((sb0 + 16) ^ sswz)) = k1;
      *(u32x4*)(vsb + ((sb0 + 0) ^ sswz)) = v0;
      *(u32x4*)(vsb + ((sb0 + 16) ^ sswz)) = v1;
    }
    __syncthreads();

    // S = (Q K^T)
    f32x4 s[4];
#pragma unroll
    for (int cb = 0; cb < 4; cb++) {
      int krow = cb * 16 + c;
      u32 kswz = (u32)((krow & 7) << 4);
      u32 kb0 = (u32)(krow * 128 + g * 16);
      u32x4 bk0 = *(const u32x4*)(ksb + ((kb0 + 0) ^ kswz));
      u32x4 bk1 = *(const u32x4*)(ksb + ((kb0 + 64) ^ kswz));
      f32x4 t = f32x4{0.f, 0.f, 0.f, 0.f};
      mfma_b16(t, aq0, bk0);
      mfma_b16(t, aq1, bk1);
      s[cb] = t;
    }
    mfma_fence();
#pragma unroll
    for (int cb = 0; cb < 4; cb++)
#pragma unroll
      for (int r = 0; r < 4; r++) s[cb][r] *= 0.125f;

    // sparse bias walk (index-sorted lists)
#pragma unroll
    for (int r = 0; r < 4; r++) {
      int rowl = w * 16 + 4 * g + r;
      int p = ptr4[r];
      while (p < 32) {
        int j = idxs[rowl * 32 + p];
        if (j >= jt + 64) break;
        float wv = wss[rowl * 32 + p];
        int jl = j - jt;
        float add = ((jl & 15) == c) ? wv : 0.f;
        int cbj = jl >> 4;
        s[0][r] += (cbj == 0) ? add : 0.f;
        s[1][r] += (cbj == 1) ? add : 0.f;
        s[2][r] += (cbj == 2) ? add : 0.f;
        s[3][r] += (cbj == 3) ? add : 0.f;
        p++;
      }
      ptr4[r] = p;
    }

    // online softmax
    float pv[4][4];
#pragma unroll
    for (int r = 0; r < 4; r++) {
      float tm = fmaxf(fmaxf(s[0][r], s[1][r]), fmaxf(s[2][r], s[3][r]));
#pragma unroll
      for (int off = 1; off < 16; off <<= 1) tm = fmaxf(tm, __shfl_xor(tm, off, 64));
      float mn = fmaxf(mrow[r], tm);
      float f = EXP2F((mrow[r] - mn) * LOG2E);
      mrow[r] = mn;
      float lsum = 0.f;
#pragma unroll
      for (int cb = 0; cb < 4; cb++) {
        float e = EXP2F((s[cb][r] - mn) * LOG2E);
        pv[cb][r] = e;
        lsum += e;
      }
      ssum[r] = ssum[r] * f + lsum;
      o[0][r] *= f;
      o[1][r] *= f;
      o[2][r] *= f;
      o[3][r] *= f;
    }

    // P -> per-wave LDS (bf16, swizzled)
#pragma unroll
    for (int r = 0; r < 4; r++) {
      int prow = 4 * g + r;
      u32 pswz = (u32)((prow & 7) << 4);
#pragma unroll
      for (int cb = 0; cb < 4; cb++) {
        u32 pbyte = (u32)(prow * 128 + (cb * 16 + c) * 2) ^ pswz;
        *(u16*)(pwb + pbyte) = f2bf(pv[cb][r]);
      }
    }

    // O += P V
    u32 abyte = (u32)(c * 128 + g * 16);
    u32 aswz = (u32)((c & 7) << 4);
    u32x4 ap0 = *(const u32x4*)(pwb + ((abyte + 0) ^ aswz));
    u32x4 ap1 = *(const u32x4*)(pwb + ((abyte + 64) ^ aswz));
#pragma unroll
    for (int db = 0; db < 4; db++) {
      int vrow = db * 16 + c;
      u32 vswz = (u32)((vrow & 7) << 4);
      u32 vb0 = (u32)(vrow * 128 + g * 16);
      u32x4 bv0 = *(const u32x4*)(vsb + ((vb0 + 0) ^ vswz));
      u32x4 bv1 = *(const u32x4*)(vsb + ((vb0 + 64) ^ vswz));
      mfma_b16(o[db], ap0, bv0);
      mfma_b16(o[db], ap1, bv1);
    }
  }
  mfma_fence();
#pragma unroll
  for (int r = 0; r < 4; r++) {
    float t = ssum[r];
#pragma unroll
    for (int off = 1; off < 16; off <<= 1) t += __shfl_xor(t, off, 64);
    ssum[r] = 1.f / t;
  }
#pragma unroll
  for (int db = 0; db < 4; db++) {
#pragma unroll
    for (int r = 0; r < 4; r++) {
      int nn = qbase + w * 16 + 4 * g + r;
      int dcol = h * 64 + db * 16 + c;
      attnout[((size_t)b * 2048 + nn) * 512 + dcol] = o[db][r] * ssum[r];
    }
  }
}

// ---------------------------------------------------------------------------
extern "C" void kernel_launch(void* const* d_in, const int* in_sizes, int n_in,
                              void* d_out, int out_size, void* d_ws, size_t ws_size,
                              hipStream_t stream) {
  (void)in_sizes; (void)n_in; (void)out_size; (void)ws_size;
  const float* x = (const float*)d_in[0];
  const float* sim = (const float*)d_in[1];
  const float* Wq = (const float*)d_in[2];
  const float* bq = (const float*)d_in[3];
  const float* Wk = (const float*)d_in[4];
  const float* bk = (const float*)d_in[5];
  const float* Wv = (const float*)d_in[6];
  const float* bv = (const float*)d_in[7];
  const float* Wo = (const float*)d_in[8];
  const float* bo = (const float*)d_in[9];
  const float* tau = (const float*)d_in[10];
  float* out = (float*)d_out;

  char* ws = (char*)d_ws;
  size_t off = 0;
  auto alloc = [&](size_t bytes) {
    void* p = ws + off;
    off += (bytes + 255) & ~(size_t)255;
    return p;
  };
  u16* WqkvT = (u16*)alloc((size_t)1536 * 256 * 2);
  u16* WoT = (u16*)alloc((size_t)512 * 512 * 2);
  float* biasQKV = (float*)alloc((size_t)1536 * 4);
  u16* Qb = (u16*)alloc((size_t)32 * 2048 * 64 * 2);
  u16* Kb = (u16*)alloc((size_t)32 * 2048 * 64 * 2);
  u16* Vb = (u16*)alloc((size_t)32 * 2048 * 64 * 2);
  u16* Vt = (u16*)alloc((size_t)32 * 2048 * 64 * 2);
  float* attnout = (float*)alloc((size_t)8192 * 512 * 4);
  int* tix = (int*)alloc((size_t)8192 * 32 * 4);
  float* tww = (float*)alloc((size_t)8192 * 32 * 4);

  prep_kernel<<<dim3(256), dim3(256), 0, stream>>>(Wq, Wk, Wv, Wo, bq, bk, bv, WqkvT, WoT,
                                                   biasQKV);
  topk_kernel<<<dim3(2048), dim3(256), 0, stream>>>(sim, tau, tix, tww);
  gemm_nt<0><<<dim3(12, 64), dim3(256), 0, stream>>>(x, WqkvT, biasQKV, Qb, Kb, Vb, nullptr,
                                                     8192, 1536, 256);
  transpose_v<<<dim3(32, 32), dim3(256), 0, stream>>>(Vb, Vt);
  attn_kernel<<<dim3(32, 32), dim3(256), 0, stream>>>(Qb, Kb, Vt, tix, tww, attnout);
  gemm_nt<1><<<dim3(4, 64), dim3(256), 0, stream>>>(attnout, WoT, bo, nullptr, nullptr, nullptr,
                                                    out, 8192, 512, 512);
}

// Round 3
// 386.050 us; speedup vs baseline: 1.1892x; 1.1892x over previous
//
#include <hip/hip_runtime.h>

typedef unsigned int u32;
typedef unsigned short u16;
typedef unsigned long long u64;
typedef float f32x4 __attribute__((ext_vector_type(4)));
typedef u32 u32x4 __attribute__((ext_vector_type(4)));
typedef u32 u32x2 __attribute__((ext_vector_type(2)));

#define DEVINL static __device__ __forceinline__
#define LOG2E 1.44269504088896340736f
#define QSCALE 0.18033688011112042f /* 0.125 * LOG2E */

DEVINL u16 f2bf(float f) {
  u32 u = __builtin_bit_cast(u32, f);
  u32 r = u + 0x7FFFu + ((u >> 16) & 1u);
  return (u16)(r >> 16);
}

DEVINL u32 cvtpk(float lo, float hi) {
  u32 r;
  asm("v_cvt_pk_bf16_f32 %0, %1, %2" : "=v"(r) : "v"(lo), "v"(hi));
  return r;
}
DEVINL float exp2v(float x) {
  float r;
  asm("v_exp_f32 %0, %1" : "=v"(r) : "v"(x));
  return r;
}
DEVINL void mfma_b16(f32x4& c, u32x4 a, u32x4 b) {
  asm volatile("v_mfma_f32_16x16x32_bf16 %0, %1, %2, %0" : "+v"(c) : "v"(a), "v"(b));
}
DEVINL void mfma_fence() { asm volatile("s_nop 7\n\ts_nop 7"); }

// ---------------------------------------------------------------------------
// prep: x -> bf16; tiled transpose of Wq/Wk/Wv -> WqkvT [1536][256] bf16 and
// Wo -> WoT [512][512] bf16; concat qkv bias. Grid = 1024 + 96 + 64 + 1.
// ---------------------------------------------------------------------------
__global__ __launch_bounds__(256) void prep_kernel(
    const float* __restrict__ x, const float* __restrict__ Wq, const float* __restrict__ Wk,
    const float* __restrict__ Wv, const float* __restrict__ Wo, const float* __restrict__ bq,
    const float* __restrict__ bk, const float* __restrict__ bv, u16* __restrict__ xb,
    u16* __restrict__ WqkvT, u16* __restrict__ WoT, float* __restrict__ biasQKV) {
  __shared__ float T[64][65];
  const int blk = blockIdx.x, tid = threadIdx.x;
  if (blk < 1024) {  // x convert: 2,097,152 elems, 8/thread
    int i0 = (blk * 256 + tid) * 8;
    f32x4 v0 = *(const f32x4*)(x + i0);
    f32x4 v1 = *(const f32x4*)(x + i0 + 4);
    u32x4 pk;
    pk[0] = (u32)f2bf(v0[0]) | ((u32)f2bf(v0[1]) << 16);
    pk[1] = (u32)f2bf(v0[2]) | ((u32)f2bf(v0[3]) << 16);
    pk[2] = (u32)f2bf(v1[0]) | ((u32)f2bf(v1[1]) << 16);
    pk[3] = (u32)f2bf(v1[2]) | ((u32)f2bf(v1[3]) << 16);
    *(u32x4*)(xb + i0) = pk;
    return;
  }
  if (blk < 1024 + 96 + 64) {  // weight transposes, 64x64 f32 tiles
    int t = blk - 1024;
    const float* W;
    u16* dst;
    int k0, n0, outld, outrow0;
    if (t < 96) {
      int sel = t >> 5, tt = t & 31;
      W = sel == 0 ? Wq : (sel == 1 ? Wk : Wv);
      k0 = (tt >> 3) * 64;
      n0 = (tt & 7) * 64;
      dst = WqkvT;
      outld = 256;
      outrow0 = sel * 512 + n0;
    } else {
      int tt = t - 96;
      W = Wo;
      k0 = (tt >> 3) * 64;
      n0 = (tt & 7) * 64;
      dst = WoT;
      outld = 512;
      outrow0 = n0;
    }
    const int r = tid >> 2, q = tid & 3;
#pragma unroll
    for (int i = 0; i < 4; i++) {
      f32x4 vv = *(const f32x4*)(W + (size_t)(k0 + r) * 512 + n0 + q * 16 + i * 4);
      T[r][q * 16 + i * 4 + 0] = vv[0];
      T[r][q * 16 + i * 4 + 1] = vv[1];
      T[r][q * 16 + i * 4 + 2] = vv[2];
      T[r][q * 16 + i * 4 + 3] = vv[3];
    }
    __syncthreads();
    u16 tmpv[16];
#pragma unroll
    for (int e = 0; e < 16; e++) tmpv[e] = f2bf(T[q * 16 + e][r]);
    u32x4 w0, w1;
#pragma unroll
    for (int j = 0; j < 4; j++) {
      w0[j] = (u32)tmpv[2 * j] | ((u32)tmpv[2 * j + 1] << 16);
      w1[j] = (u32)tmpv[8 + 2 * j] | ((u32)tmpv[9 + 2 * j] << 16);
    }
    u16* dp = dst + (size_t)(outrow0 + r) * outld + k0 + q * 16;
    *(u32x4*)dp = w0;
    *(u32x4*)(dp + 8) = w1;
    return;
  }
  for (int i = tid; i < 1536; i += 256)
    biasQKV[i] = i < 512 ? bq[i] : (i < 1024 ? bk[i - 512] : bv[i - 1024]);
}

// ---------------------------------------------------------------------------
// topk: one wave per row; exact f32 top-32 with jax tie-break (lower index).
// Output: per row, 32 packed entries (idx<<16 | bf16(tau*w*LOG2E)) sorted by
// (g-bucket=(idx>>2)&3, idx), plus packed bucket starts.
// ---------------------------------------------------------------------------
__global__ __launch_bounds__(256) void topk_kernel(const float* __restrict__ sim,
                                                   const float* __restrict__ tau_raw,
                                                   u32* __restrict__ tpw,
                                                   u32* __restrict__ tstarts) {
  const int tid = threadIdx.x, lane = tid & 63, w = tid >> 6;
  const int row = blockIdx.x * 4 + w;
  const int b = row >> 11, n = row & 2047;
  const float* src = sim + ((size_t)b * 2048 + n) * 2048;

  float vals[32];
#pragma unroll
  for (int q = 0; q < 8; q++) {
    f32x4 v = *(const f32x4*)(src + q * 256 + lane * 4);
#pragma unroll
    for (int j = 0; j < 4; j++) {
      int m = (q << 8) + lane * 4 + j;
      float xv = fmaxf(v[j], 0.f);
      vals[q * 4 + j] = (m == n) ? -1e30f : xv;
    }
  }
  u32 used = 0;
  float bv;
  int bm;
  auto rescan = [&]() {
    bv = -2e30f;
    bm = 0x7fffffff;
#pragma unroll
    for (int e = 0; e < 32; e++) {
      float v = ((used >> e) & 1u) ? -2e30f : vals[e];
      int m = ((e >> 2) << 8) + lane * 4 + (e & 3);
      bool take = (v > bv) || (v == bv && m < bm);
      bv = take ? v : bv;
      bm = take ? m : bm;
    }
  };
  rescan();
  int myidx = 0;
  float myval = 0.f;
  for (int it = 0; it < 32; it++) {
    float cv = bv;
    int cm = bm;
#pragma unroll
    for (int off = 1; off < 64; off <<= 1) {
      float ov = __shfl_xor(cv, off, 64);
      int om = __shfl_xor(cm, off, 64);
      bool take = (ov > cv) || (ov == cv && om < cm);
      cv = take ? ov : cv;
      cm = take ? om : cm;
    }
    if (lane == it) { myidx = cm; myval = cv; }
    if (cm == bm) {
      used |= 1u << (((cm >> 8) << 2) | (cm & 3));
      rescan();
    }
  }
  float sv = (lane < 32) ? myval : 0.f;
#pragma unroll
  for (int off = 1; off < 64; off <<= 1) sv += __shfl_xor(sv, off, 64);
  float tau = log1pf(__expf(tau_raw[0]));
  float wvv = tau * myval / fmaxf(sv, 1e-8f) * LOG2E;

  int bucket = (myidx >> 2) & 3;
  u64 bm0 = __ballot(lane < 32 && bucket == 0);
  u64 bm1 = __ballot(lane < 32 && bucket == 1);
  u64 bm2 = __ballot(lane < 32 && bucket == 2);
  int c0 = __popcll(bm0), c1 = __popcll(bm1), c2 = __popcll(bm2);
  int key = (bucket << 11) | myidx;
  int rank = 0;
  for (int j2 = 0; j2 < 32; j2++) {
    int ok = __shfl(key, j2, 64);
    rank += (ok < key) ? 1 : 0;
  }
  if (lane < 32) tpw[(size_t)row * 32 + rank] = ((u32)myidx << 16) | (u32)f2bf(wvv);
  if (lane == 0)
    tstarts[row] = ((u32)c0 << 8) | ((u32)(c0 + c1) << 16) | ((u32)(c0 + c1 + c2) << 24);
}

// ---------------------------------------------------------------------------
// NT GEMM: A [M][K] bf16, Bt [N][K] bf16, 128x128 tile, BK=32, 4 waves.
// MODE 0: scatter bf16 to Q/K/V head-split buffers (Q pre-scaled by QSCALE).
// MODE 1: f32 out [M][N].
// ---------------------------------------------------------------------------
template <int MODE>
__global__ __launch_bounds__(256) void gemm_nt(const u16* __restrict__ A,
                                               const u16* __restrict__ Bt,
                                               const float* __restrict__ bias,
                                               u16* __restrict__ outQ, u16* __restrict__ outK,
                                               u16* __restrict__ outV, float* __restrict__ outF,
                                               int M, int N, int K) {
  __shared__ __align__(16) u16 As[128 * 32];
  __shared__ __align__(16) u16 Bs[128 * 32];

  const int tid = threadIdx.x;
  const int lane = tid & 63;
  const int w = tid >> 6;
  const int g = lane >> 4, c = lane & 15;
  const int wr = (w >> 1) * 64, wc = (w & 1) * 64;
  const int m0 = blockIdx.y * 128, n0 = blockIdx.x * 128;

  f32x4 acc[4][4];
#pragma unroll
  for (int i = 0; i < 4; i++)
#pragma unroll
    for (int j = 0; j < 4; j++) acc[i][j] = f32x4{0.f, 0.f, 0.f, 0.f};

  const int srow = tid >> 1;
  const int shalf = tid & 1;
  const u16* Arow = A + (size_t)(m0 + srow) * K + shalf * 16;
  const u16* Brow = Bt + (size_t)(n0 + srow) * K + shalf * 16;
  char* asbase = (char*)As;
  char* bsbase = (char*)Bs;
  const u32 swz = (u32)((srow & 7) << 4);
  const u32 wb0 = (u32)(srow * 64 + shalf * 32);

  for (int kt = 0; kt < K; kt += 32) {
    __syncthreads();
    {
      u32x4 a0 = *(const u32x4*)(Arow + kt);
      u32x4 a1 = *(const u32x4*)(Arow + kt + 8);
      u32x4 b0 = *(const u32x4*)(Brow + kt);
      u32x4 b1 = *(const u32x4*)(Brow + kt + 8);
      *(u32x4*)(asbase + ((wb0 + 0) ^ swz)) = a0;
      *(u32x4*)(asbase + ((wb0 + 16) ^ swz)) = a1;
      *(u32x4*)(bsbase + ((wb0 + 0) ^ swz)) = b0;
      *(u32x4*)(bsbase + ((wb0 + 16) ^ swz)) = b1;
    }
    __syncthreads();
    u32x4 af[4], bfr[4];
#pragma unroll
    for (int fr = 0; fr < 4; fr++) {
      int row = wr + fr * 16 + c;
      af[fr] = *(const u32x4*)(asbase + ((u32)(row * 64 + g * 16) ^ ((u32)((row & 7) << 4))));
    }
#pragma unroll
    for (int fc = 0; fc < 4; fc++) {
      int row = wc + fc * 16 + c;
      bfr[fc] = *(const u32x4*)(bsbase + ((u32)(row * 64 + g * 16) ^ ((u32)((row & 7) << 4))));
    }
#pragma unroll
    for (int fr = 0; fr < 4; fr++)
#pragma unroll
      for (int fc = 0; fc < 4; fc++) mfma_b16(acc[fr][fc], af[fr], bfr[fc]);
  }
  mfma_fence();
#pragma unroll
  for (int fc = 0; fc < 4; fc++) {
    int gcol = n0 + wc + fc * 16 + c;
    float bvv = bias[gcol];
#pragma unroll
    for (int fr = 0; fr < 4; fr++) {
#pragma unroll
      for (int r = 0; r < 4; r++) {
        int grow = m0 + wr + fr * 16 + 4 * g + r;
        float v = acc[fr][fc][r] + bvv;
        if (MODE == 0) {
          int sel = gcol >> 9, c9 = gcol & 511;
          if (sel == 0) v *= QSCALE;
          int hh = c9 >> 6, dd = c9 & 63;
          int bb = grow >> 11, nn = grow & 2047;
          size_t off2 = ((size_t)(bb * 8 + hh) * 2048 + nn) * 64 + dd;
          u16* dst = sel == 0 ? outQ : (sel == 1 ? outK : outV);
          dst[off2] = f2bf(v);
        } else {
          outF[(size_t)grow * N + gcol] = v;
        }
      }
    }
  }
}

// ---------------------------------------------------------------------------
// transpose V: [BH][N][64] -> [BH][64][N] (bf16)
// ---------------------------------------------------------------------------
__global__ __launch_bounds__(256) void transpose_v(const u16* __restrict__ Vb,
                                                   u16* __restrict__ Vt) {
  __shared__ __align__(16) u16 T[64 * 72];
  const int nt = blockIdx.x, bh = blockIdx.y;
  const int tid = threadIdx.x;
  const int rr = tid >> 2, q = tid & 3;
  {
    const u16* src = Vb + ((size_t)bh * 2048 + nt * 64 + rr) * 64 + q * 16;
    u32x4 a = *(const u32x4*)src;
    u32x4 b = *(const u32x4*)(src + 8);
    *(u32x4*)(&T[rr * 72 + q * 16]) = a;
    *(u32x4*)(&T[rr * 72 + q * 16 + 8]) = b;
  }
  __syncthreads();
  {
    union { u16 s[16]; u32x4 v[2]; } ou;
#pragma unroll
    for (int e = 0; e < 16; e++) ou.s[e] = T[(q * 16 + e) * 72 + rr];
    u16* dst = Vt + ((size_t)bh * 64 + rr) * 2048 + nt * 64 + q * 16;
    *(u32x4*)dst = ou.v[0];
    *(u32x4*)(dst + 8) = ou.v[1];
  }
}

// ---------------------------------------------------------------------------
// flash attention, swapped-QK^T (S^T = mfma(K,Q)): lane owns one q-column.
// Q pre-scaled by 0.125*LOG2E -> softmax in exp2 domain. Sparse bias via
// g-bucketed per-row lists. Defer-max (THR=8). Output bf16 [B*N][512].
// Grid: 1024 flat, XCD-grouped so all 32 q-tiles of one bh share an XCD.
// ---------------------------------------------------------------------------
__global__ __launch_bounds__(256) void attn_kernel(const u16* __restrict__ Qb,
                                                   const u16* __restrict__ Kb,
                                                   const u16* __restrict__ Vt,
                                                   const u32* __restrict__ tpw,
                                                   const u32* __restrict__ tstarts,
                                                   u16* __restrict__ attnout) {
  __shared__ __align__(16) u16 Ks[64 * 64];
  __shared__ __align__(16) u16 Vs[64 * 64];
  __shared__ __align__(16) u16 Ps[4][16 * 64];
  __shared__ u32 pws[64 * 32];
  __shared__ u32 tst[64];

  const int bid = blockIdx.x;
  const int bh = (bid & 7) * 4 + ((bid >> 3) & 3);
  const int qt = bid >> 5;
  const int b = bh >> 3, h = bh & 7;
  const int tid = threadIdx.x, lane = tid & 63, w = tid >> 6;
  const int g = lane >> 4, c = lane & 15;
  const int qbase = qt * 64;

  for (int i = tid; i < 2048; i += 256)
    pws[i] = tpw[((size_t)b * 2048 + qbase) * 32 + i];
  if (tid < 64) tst[tid] = tstarts[b * 2048 + qbase + tid];

  const u16* qptr = Qb + ((size_t)bh * 2048 + qbase + w * 16 + c) * 64 + g * 8;
  u32x4 aq0 = *(const u32x4*)qptr;
  u32x4 aq1 = *(const u32x4*)(qptr + 32);

  float m = -1e30f, ssum = 0.f;
  f32x4 o[4];
#pragma unroll
  for (int db = 0; db < 4; db++) o[db] = f32x4{0.f, 0.f, 0.f, 0.f};

  const int rowl = w * 16 + c;

  const int sr = tid >> 2, sq = tid & 3;
  const u16* ksrc = Kb + ((size_t)bh * 2048 + sr) * 64 + sq * 16;
  const u16* vsrc = Vt + ((size_t)bh * 64 + sr) * 2048 + sq * 16;
  char* ksb = (char*)Ks;
  char* vsb = (char*)Vs;
  char* pwb = (char*)&Ps[w][0];
  const u32 sswz = (u32)((sr & 7) << 4);
  const u32 sb0 = (u32)(sr * 128 + sq * 32);

  // hoisted LDS offsets (rows db*16+c / cb*16+c are the same set)
  u32 koff[4][2], poff2[2], pwoff[4][2];
#pragma unroll
  for (int cb = 0; cb < 4; cb++) {
    int row = cb * 16 + c;
    u32 sz = (u32)((row & 7) << 4);
    koff[cb][0] = ((u32)(row * 128 + g * 16)) ^ sz;
    koff[cb][1] = ((u32)(row * 128 + g * 16 + 64)) ^ sz;
  }
  {
    u32 sz = (u32)((c & 7) << 4);
#pragma unroll
    for (int mm = 0; mm < 2; mm++) poff2[mm] = ((u32)(c * 128 + mm * 64 + g * 16)) ^ sz;
#pragma unroll
    for (int cb = 0; cb < 4; cb++)
#pragma unroll
      for (int hh = 0; hh < 2; hh++)
        pwoff[cb][hh] = ((u32)(c * 128 + cb * 32 + g * 8 + hh * 4)) ^ sz;
  }

  __syncthreads();
  u32 stw = tst[rowl];
  int p = (int)((stw >> (8 * g)) & 255u);
  const int pend = (g == 3) ? 32 : (int)((stw >> (8 * g + 8)) & 255u);

  for (int jt = 0; jt < 2048; jt += 64) {
    __syncthreads();
    {
      u32x4 k0 = *(const u32x4*)(ksrc + (size_t)jt * 64);
      u32x4 k1 = *(const u32x4*)(ksrc + (size_t)jt * 64 + 8);
      u32x4 v0 = *(const u32x4*)(vsrc + jt);
      u32x4 v1 = *(const u32x4*)(vsrc + jt + 8);
      *(u32x4*)(ksb + ((sb0 + 0) ^ sswz)) = k0;
      *(u32x4*)(ksb + ((sb0 + 16) ^ sswz)) = k1;
      *(u32x4*)(vsb + ((sb0 + 0) ^ sswz)) = v0;
      *(u32x4*)(vsb + ((sb0 + 16) ^ sswz)) = v1;
    }
    __syncthreads();

    // S^T = K Q^T: lane holds S[kv=jt+16cb+4g+r][q=rowl]
    f32x4 s[4];
#pragma unroll
    for (int cb = 0; cb < 4; cb++) {
      u32x4 bk0 = *(const u32x4*)(ksb + koff[cb][0]);
      u32x4 bk1 = *(const u32x4*)(ksb + koff[cb][1]);
      f32x4 t = f32x4{0.f, 0.f, 0.f, 0.f};
      mfma_b16(t, bk0, aq0);
      mfma_b16(t, bk1, aq1);
      s[cb] = t;
    }
    mfma_fence();

    // sparse bias (this lane's g-bucket only)
    const int jtend = jt + 64;
    while (p < pend) {
      u32 e = pws[rowl * 32 + p];
      int j = (int)(e >> 16);
      if (j >= jtend) break;
      float wv = __builtin_bit_cast(float, e << 16);
      int rel = j - jt - 4 * g;
#pragma unroll
      for (int cb = 0; cb < 4; cb++)
#pragma unroll
        for (int r = 0; r < 4; r++) s[cb][r] += (rel == cb * 16 + r) ? wv : 0.f;
      p++;
    }

    // online softmax (exp2 domain), defer-max THR=8
    float tm = fmaxf(fmaxf(fmaxf(s[0][0], s[0][1]), fmaxf(s[0][2], s[0][3])),
                     fmaxf(fmaxf(s[1][0], s[1][1]), fmaxf(s[1][2], s[1][3])));
    tm = fmaxf(tm, fmaxf(fmaxf(fmaxf(s[2][0], s[2][1]), fmaxf(s[2][2], s[2][3])),
                         fmaxf(fmaxf(s[3][0], s[3][1]), fmaxf(s[3][2], s[3][3]))));
    tm = fmaxf(tm, __shfl_xor(tm, 16, 64));
    tm = fmaxf(tm, __shfl_xor(tm, 32, 64));
    if (!__all(tm - m <= 8.f)) {
      float mn = fmaxf(m, tm);
      float f = exp2v(m - mn);
      m = mn;
      ssum *= f;
#pragma unroll
      for (int db = 0; db < 4; db++) o[db] *= f;
    }
    float lsum = 0.f;
#pragma unroll
    for (int cb = 0; cb < 4; cb++) {
      float e0 = exp2v(s[cb][0] - m);
      float e1 = exp2v(s[cb][1] - m);
      float e2 = exp2v(s[cb][2] - m);
      float e3 = exp2v(s[cb][3] - m);
      lsum += (e0 + e1) + (e2 + e3);
      *(u32*)(pwb + pwoff[cb][0]) = cvtpk(e0, e1);
      *(u32*)(pwb + pwoff[cb][1]) = cvtpk(e2, e3);
    }
    ssum += lsum;

    // O^T += V^T P : o[db] cols q=c, rows d=db*16+4g+r
    u32x4 pf0 = *(const u32x4*)(pwb + poff2[0]);
    u32x4 pf1 = *(const u32x4*)(pwb + poff2[1]);
#pragma unroll
    for (int db = 0; db < 4; db++) {
      u32x4 bv0 = *(const u32x4*)(vsb + koff[db][0]);
      u32x4 bv1 = *(const u32x4*)(vsb + koff[db][1]);
      mfma_b16(o[db], bv0, pf0);
      mfma_b16(o[db], bv1, pf1);
    }
    mfma_fence();
  }

  ssum += __shfl_xor(ssum, 16, 64);
  ssum += __shfl_xor(ssum, 32, 64);
  float inv = 1.f / ssum;
  const int n = qbase + w * 16 + c;
  u16* obase = attnout + ((size_t)b * 2048 + n) * 512 + h * 64 + 4 * g;
#pragma unroll
  for (int db = 0; db < 4; db++) {
    u32x2 st;
    st[0] = cvtpk(o[db][0] * inv, o[db][1] * inv);
    st[1] = cvtpk(o[db][2] * inv, o[db][3] * inv);
    *(u32x2*)(obase + db * 16) = st;
  }
}

// ---------------------------------------------------------------------------
extern "C" void kernel_launch(void* const* d_in, const int* in_sizes, int n_in,
                              void* d_out, int out_size, void* d_ws, size_t ws_size,
                              hipStream_t stream) {
  (void)in_sizes; (void)n_in; (void)out_size; (void)ws_size;
  const float* x = (const float*)d_in[0];
  const float* sim = (const float*)d_in[1];
  const float* Wq = (const float*)d_in[2];
  const float* bq = (const float*)d_in[3];
  const float* Wk = (const float*)d_in[4];
  const float* bk = (const float*)d_in[5];
  const float* Wv = (const float*)d_in[6];
  const float* bv = (const float*)d_in[7];
  const float* Wo = (const float*)d_in[8];
  const float* bo = (const float*)d_in[9];
  const float* tau = (const float*)d_in[10];
  float* out = (float*)d_out;

  char* ws = (char*)d_ws;
  size_t off = 0;
  auto alloc = [&](size_t bytes) {
    void* p = ws + off;
    off += (bytes + 255) & ~(size_t)255;
    return p;
  };
  u16* xb = (u16*)alloc((size_t)8192 * 256 * 2);
  u16* WqkvT = (u16*)alloc((size_t)1536 * 256 * 2);
  u16* WoT = (u16*)alloc((size_t)512 * 512 * 2);
  float* biasQKV = (float*)alloc((size_t)1536 * 4);
  u16* Qb = (u16*)alloc((size_t)32 * 2048 * 64 * 2);
  u16* Kb = (u16*)alloc((size_t)32 * 2048 * 64 * 2);
  u16* Vb = (u16*)alloc((size_t)32 * 2048 * 64 * 2);
  u16* Vt = (u16*)alloc((size_t)32 * 2048 * 64 * 2);
  u16* attnout = (u16*)alloc((size_t)8192 * 512 * 2);
  u32* tpw = (u32*)alloc((size_t)8192 * 32 * 4);
  u32* tstarts = (u32*)alloc((size_t)8192 * 4);

  prep_kernel<<<dim3(1185), dim3(256), 0, stream>>>(x, Wq, Wk, Wv, Wo, bq, bk, bv, xb, WqkvT,
                                                    WoT, biasQKV);
  topk_kernel<<<dim3(2048), dim3(256), 0, stream>>>(sim, tau, tpw, tstarts);
  gemm_nt<0><<<dim3(12, 64), dim3(256), 0, stream>>>(xb, WqkvT, biasQKV, Qb, Kb, Vb, nullptr,
                                                     8192, 1536, 256);
  transpose_v<<<dim3(32, 32), dim3(256), 0, stream>>>(Vb, Vt);
  attn_kernel<<<dim3(1024), dim3(256), 0, stream>>>(Qb, Kb, Vt, tpw, tstarts, attnout);
  gemm_nt<1><<<dim3(4, 64), dim3(256), 0, stream>>>(attnout, WoT, bo, nullptr, nullptr, nullptr,
                                                    out, 8192, 512, 512);
}

// Round 4
// 256.531 us; speedup vs baseline: 1.7895x; 1.5049x over previous
//
#include <hip/hip_runtime.h>

typedef unsigned int u32;
typedef unsigned short u16;
typedef unsigned long long u64;
typedef float f32x4 __attribute__((ext_vector_type(4)));
typedef u32 u32x4 __attribute__((ext_vector_type(4)));
typedef u32 u32x2 __attribute__((ext_vector_type(2)));

#define DEVINL static __device__ __forceinline__
#define LOG2E 1.44269504088896340736f
#define QSCALE 0.18033688011112042f /* 0.125 * LOG2E */

DEVINL u16 f2bf(float f) {
  u32 u = __builtin_bit_cast(u32, f);
  u32 r = u + 0x7FFFu + ((u >> 16) & 1u);
  return (u16)(r >> 16);
}

DEVINL u32 cvtpk(float lo, float hi) {
  u32 r;
  asm("v_cvt_pk_bf16_f32 %0, %1, %2" : "=v"(r) : "v"(lo), "v"(hi));
  return r;
}
DEVINL float exp2v(float x) {
  float r;
  asm("v_exp_f32 %0, %1" : "=v"(r) : "v"(x));
  return r;
}
DEVINL void mfma_b16(f32x4& c, u32x4 a, u32x4 b) {
  asm volatile("v_mfma_f32_16x16x32_bf16 %0, %1, %2, %0" : "+v"(c) : "v"(a), "v"(b));
}
DEVINL void mfma_fence() { asm volatile("s_nop 7\n\ts_nop 7"); }

DEVINL int mbcnt64(u64 m) {
  return __builtin_amdgcn_mbcnt_hi((u32)(m >> 32), __builtin_amdgcn_mbcnt_lo((u32)m, 0));
}
DEVINL u64 shfl_xor64(u64 v, int m) {
  u32 lo = (u32)v, hi = (u32)(v >> 32);
  lo = __shfl_xor(lo, m, 64);
  hi = __shfl_xor(hi, m, 64);
  return ((u64)hi << 32) | lo;
}

// ---------------------------------------------------------------------------
// prep: x -> bf16; tiled transpose of Wq/Wk/Wv -> WqkvT [1536][256] bf16 and
// Wo -> WoT [512][512] bf16; concat qkv bias. Grid = 1024 + 96 + 64 + 1.
// ---------------------------------------------------------------------------
__global__ __launch_bounds__(256) void prep_kernel(
    const float* __restrict__ x, const float* __restrict__ Wq, const float* __restrict__ Wk,
    const float* __restrict__ Wv, const float* __restrict__ Wo, const float* __restrict__ bq,
    const float* __restrict__ bk, const float* __restrict__ bv, u16* __restrict__ xb,
    u16* __restrict__ WqkvT, u16* __restrict__ WoT, float* __restrict__ biasQKV) {
  __shared__ float T[64][65];
  const int blk = blockIdx.x, tid = threadIdx.x;
  if (blk < 1024) {  // x convert: 2,097,152 elems, 8/thread
    int i0 = (blk * 256 + tid) * 8;
    f32x4 v0 = *(const f32x4*)(x + i0);
    f32x4 v1 = *(const f32x4*)(x + i0 + 4);
    u32x4 pk;
    pk[0] = (u32)f2bf(v0[0]) | ((u32)f2bf(v0[1]) << 16);
    pk[1] = (u32)f2bf(v0[2]) | ((u32)f2bf(v0[3]) << 16);
    pk[2] = (u32)f2bf(v1[0]) | ((u32)f2bf(v1[1]) << 16);
    pk[3] = (u32)f2bf(v1[2]) | ((u32)f2bf(v1[3]) << 16);
    *(u32x4*)(xb + i0) = pk;
    return;
  }
  if (blk < 1024 + 96 + 64) {  // weight transposes, 64x64 f32 tiles
    int t = blk - 1024;
    const float* W;
    u16* dst;
    int k0, n0, outld, outrow0;
    if (t < 96) {
      int sel = t >> 5, tt = t & 31;
      W = sel == 0 ? Wq : (sel == 1 ? Wk : Wv);
      k0 = (tt >> 3) * 64;
      n0 = (tt & 7) * 64;
      dst = WqkvT;
      outld = 256;
      outrow0 = sel * 512 + n0;
    } else {
      int tt = t - 96;
      W = Wo;
      k0 = (tt >> 3) * 64;
      n0 = (tt & 7) * 64;
      dst = WoT;
      outld = 512;
      outrow0 = n0;
    }
    const int r = tid >> 2, q = tid & 3;
#pragma unroll
    for (int i = 0; i < 4; i++) {
      f32x4 vv = *(const f32x4*)(W + (size_t)(k0 + r) * 512 + n0 + q * 16 + i * 4);
      T[r][q * 16 + i * 4 + 0] = vv[0];
      T[r][q * 16 + i * 4 + 1] = vv[1];
      T[r][q * 16 + i * 4 + 2] = vv[2];
      T[r][q * 16 + i * 4 + 3] = vv[3];
    }
    __syncthreads();
    u16 tmpv[16];
#pragma unroll
    for (int e = 0; e < 16; e++) tmpv[e] = f2bf(T[q * 16 + e][r]);
    u32x4 w0, w1;
#pragma unroll
    for (int j = 0; j < 4; j++) {
      w0[j] = (u32)tmpv[2 * j] | ((u32)tmpv[2 * j + 1] << 16);
      w1[j] = (u32)tmpv[8 + 2 * j] | ((u32)tmpv[9 + 2 * j] << 16);
    }
    u16* dp = dst + (size_t)(outrow0 + r) * outld + k0 + q * 16;
    *(u32x4*)dp = w0;
    *(u32x4*)(dp + 8) = w1;
    return;
  }
  for (int i = tid; i < 1536; i += 256)
    biasQKV[i] = i < 512 ? bq[i] : (i < 1024 ? bk[i - 512] : bv[i - 1024]);
}

// ---------------------------------------------------------------------------
// topk: one wave per row. Threshold-select (interpolation search on u32 keys,
// targeting 32<=count<=64 candidates) + ballot compaction + 64-lane bitonic
// sort by (value desc, index asc) -> exact jax top-32 set with tie-break.
// Output: per row, 32 packed entries (idx<<16 | bf16(tau*w*LOG2E)) sorted by
// (g-bucket=(idx>>2)&3, idx), plus packed bucket starts.
// ---------------------------------------------------------------------------
__global__ __launch_bounds__(256) void topk_kernel(const float* __restrict__ sim,
                                                   const float* __restrict__ tau_raw,
                                                   u32* __restrict__ tpw,
                                                   u32* __restrict__ tstarts) {
  __shared__ u32 keyA[4][64];
  __shared__ u32 idxA[4][64];
  const int tid = threadIdx.x, lane = tid & 63, w = tid >> 6;
  const int row = blockIdx.x * 4 + w;
  const int b = row >> 11, n = row & 2047;
  const float* src = sim + ((size_t)b * 2048 + n) * 2048;

  // keys: monotonic u32 encoding of clamped value; self -> 0 (never selected)
  u32 keys[32];
#pragma unroll
  for (int q = 0; q < 8; q++) {
    f32x4 v = *(const f32x4*)(src + q * 256 + lane * 4);
#pragma unroll
    for (int j = 0; j < 4; j++) {
      int m = (q << 8) + lane * 4 + j;
      float xv = fmaxf(v[j], 0.f);
      keys[q * 4 + j] = (m == n) ? 0u : (__builtin_bit_cast(u32, xv) + 1u);
    }
  }

  // find threshold P with 32 <= #{key >= P} <= 64
  u32 Plo = 1u;           // count(>=1) = 2047 >= 32
  u32 Phi = 0x7F000000u;  // count ~ 0
  u32 P = 0x3F7C0001u;    // key(0.984375): uniform-model guess for rank-48
  int c = 0;
  for (int it = 0; it < 40; ++it) {
    int lc = 0;
#pragma unroll
    for (int e = 0; e < 32; e++) lc += (keys[e] >= P) ? 1 : 0;
#pragma unroll
    for (int off = 1; off < 64; off <<= 1) lc += __shfl_xor(lc, off, 64);
    c = lc;
    if (c >= 32 && c <= 64) break;
    if (c < 32) Phi = P; else Plo = P;
    if (Phi - Plo <= 1) break;  // degenerate (>32-way tie straddle) — unreachable
    long long Pn;
    if (P >= 0x3F000000u && P <= 0x3F800000u) {
      // uniform model: ~4098 key units per unit count in [0.5,1) zone; aim mid-window
      Pn = (long long)P + (long long)(c - 48) * 4098;
    } else {
      Pn = (long long)Plo + (long long)((Phi - Plo) >> 1);
    }
    if (Pn <= (long long)Plo || Pn >= (long long)Phi)
      Pn = (long long)Plo + (long long)((Phi - Plo) >> 1);
    P = (u32)Pn;
  }

  // ballot-compact candidates (key >= P) into per-wave LDS
  u32* kws = keyA[w];
  u32* iws = idxA[w];
  int base = 0;
#pragma unroll
  for (int e = 0; e < 32; e++) {
    bool pred = keys[e] >= P;
    u64 mk = __ballot(pred);
    if (pred) {
      int slot = base + mbcnt64(mk);
      if (slot < 64) {
        kws[slot] = keys[e];
        iws[slot] = (u32)((e >> 2) * 256 + lane * 4 + (e & 3));
      }
    }
    base += __popcll(mk);
  }
  for (int s = base + lane; s < 64; s += 64) {  // pad (sorts last)
    kws[s] = 0u;
    iws[s] = 2047u;
  }

  // 64-lane bitonic, descending by (key, then ascending idx)
  u64 K = ((u64)kws[lane] << 11) | (u64)(2047u - iws[lane]);
#pragma unroll
  for (int k = 2; k <= 64; k <<= 1) {
#pragma unroll
    for (int j = k >> 1; j >= 1; j >>= 1) {
      u64 o = shfl_xor64(K, j);
      bool keepmax = (((lane & k) == 0) == ((lane & j) == 0));
      u64 mx = K > o ? K : o;
      u64 mn = K > o ? o : K;
      K = keepmax ? mx : mn;
    }
  }

  // lanes 0..31 hold the top-32
  u32 key = (u32)(K >> 11);
  int myidx = 2047 - (int)(K & 0x7FFu);
  float myval = __builtin_bit_cast(float, key - 1u);
  float sv = (lane < 32) ? myval : 0.f;
#pragma unroll
  for (int off = 1; off < 64; off <<= 1) sv += __shfl_xor(sv, off, 64);
  float tau = log1pf(__expf(tau_raw[0]));
  float wvv = tau * myval / fmaxf(sv, 1e-8f) * LOG2E;

  int bucket = (myidx >> 2) & 3;
  u64 bm0 = __ballot(lane < 32 && bucket == 0);
  u64 bm1 = __ballot(lane < 32 && bucket == 1);
  u64 bm2 = __ballot(lane < 32 && bucket == 2);
  int c0 = __popcll(bm0), c1 = __popcll(bm1), c2 = __popcll(bm2);
  int key2 = (bucket << 11) | myidx;
  int rank = 0;
  for (int j2 = 0; j2 < 32; j2++) {
    int ok = __shfl(key2, j2, 64);
    rank += (ok < key2) ? 1 : 0;
  }
  if (lane < 32) tpw[(size_t)row * 32 + rank] = ((u32)myidx << 16) | (u32)f2bf(wvv);
  if (lane == 0)
    tstarts[row] = ((u32)c0 << 8) | ((u32)(c0 + c1) << 16) | ((u32)(c0 + c1 + c2) << 24);
}

// ---------------------------------------------------------------------------
// NT GEMM: A [M][K] bf16, Bt [N][K] bf16, 128x128 tile, BK=32, 4 waves.
// MODE 0: scatter bf16 to Q/K/V head-split buffers (Q pre-scaled by QSCALE).
// MODE 1: f32 out [M][N].
// ---------------------------------------------------------------------------
template <int MODE>
__global__ __launch_bounds__(256) void gemm_nt(const u16* __restrict__ A,
                                               const u16* __restrict__ Bt,
                                               const float* __restrict__ bias,
                                               u16* __restrict__ outQ, u16* __restrict__ outK,
                                               u16* __restrict__ outV, float* __restrict__ outF,
                                               int M, int N, int K) {
  __shared__ __align__(16) u16 As[128 * 32];
  __shared__ __align__(16) u16 Bs[128 * 32];

  const int tid = threadIdx.x;
  const int lane = tid & 63;
  const int w = tid >> 6;
  const int g = lane >> 4, c = lane & 15;
  const int wr = (w >> 1) * 64, wc = (w & 1) * 64;
  const int m0 = blockIdx.y * 128, n0 = blockIdx.x * 128;

  f32x4 acc[4][4];
#pragma unroll
  for (int i = 0; i < 4; i++)
#pragma unroll
    for (int j = 0; j < 4; j++) acc[i][j] = f32x4{0.f, 0.f, 0.f, 0.f};

  const int srow = tid >> 1;
  const int shalf = tid & 1;
  const u16* Arow = A + (size_t)(m0 + srow) * K + shalf * 16;
  const u16* Brow = Bt + (size_t)(n0 + srow) * K + shalf * 16;
  char* asbase = (char*)As;
  char* bsbase = (char*)Bs;
  const u32 swz = (u32)((srow & 7) << 4);
  const u32 wb0 = (u32)(srow * 64 + shalf * 32);

  for (int kt = 0; kt < K; kt += 32) {
    __syncthreads();
    {
      u32x4 a0 = *(const u32x4*)(Arow + kt);
      u32x4 a1 = *(const u32x4*)(Arow + kt + 8);
      u32x4 b0 = *(const u32x4*)(Brow + kt);
      u32x4 b1 = *(const u32x4*)(Brow + kt + 8);
      *(u32x4*)(asbase + ((wb0 + 0) ^ swz)) = a0;
      *(u32x4*)(asbase + ((wb0 + 16) ^ swz)) = a1;
      *(u32x4*)(bsbase + ((wb0 + 0) ^ swz)) = b0;
      *(u32x4*)(bsbase + ((wb0 + 16) ^ swz)) = b1;
    }
    __syncthreads();
    u32x4 af[4], bfr[4];
#pragma unroll
    for (int fr = 0; fr < 4; fr++) {
      int row = wr + fr * 16 + c;
      af[fr] = *(const u32x4*)(asbase + ((u32)(row * 64 + g * 16) ^ ((u32)((row & 7) << 4))));
    }
#pragma unroll
    for (int fc = 0; fc < 4; fc++) {
      int row = wc + fc * 16 + c;
      bfr[fc] = *(const u32x4*)(bsbase + ((u32)(row * 64 + g * 16) ^ ((u32)((row & 7) << 4))));
    }
#pragma unroll
    for (int fr = 0; fr < 4; fr++)
#pragma unroll
      for (int fc = 0; fc < 4; fc++) mfma_b16(acc[fr][fc], af[fr], bfr[fc]);
  }
  mfma_fence();
#pragma unroll
  for (int fc = 0; fc < 4; fc++) {
    int gcol = n0 + wc + fc * 16 + c;
    float bvv = bias[gcol];
#pragma unroll
    for (int fr = 0; fr < 4; fr++) {
#pragma unroll
      for (int r = 0; r < 4; r++) {
        int grow = m0 + wr + fr * 16 + 4 * g + r;
        float v = acc[fr][fc][r] + bvv;
        if (MODE == 0) {
          int sel = gcol >> 9, c9 = gcol & 511;
          if (sel == 0) v *= QSCALE;
          int hh = c9 >> 6, dd = c9 & 63;
          int bb = grow >> 11, nn = grow & 2047;
          size_t off2 = ((size_t)(bb * 8 + hh) * 2048 + nn) * 64 + dd;
          u16* dst = sel == 0 ? outQ : (sel == 1 ? outK : outV);
          dst[off2] = f2bf(v);
        } else {
          outF[(size_t)grow * N + gcol] = v;
        }
      }
    }
  }
}

// ---------------------------------------------------------------------------
// transpose V: [BH][N][64] -> [BH][64][N] (bf16)
// ---------------------------------------------------------------------------
__global__ __launch_bounds__(256) void transpose_v(const u16* __restrict__ Vb,
                                                   u16* __restrict__ Vt) {
  __shared__ __align__(16) u16 T[64 * 72];
  const int nt = blockIdx.x, bh = blockIdx.y;
  const int tid = threadIdx.x;
  const int rr = tid >> 2, q = tid & 3;
  {
    const u16* src = Vb + ((size_t)bh * 2048 + nt * 64 + rr) * 64 + q * 16;
    u32x4 a = *(const u32x4*)src;
    u32x4 b = *(const u32x4*)(src + 8);
    *(u32x4*)(&T[rr * 72 + q * 16]) = a;
    *(u32x4*)(&T[rr * 72 + q * 16 + 8]) = b;
  }
  __syncthreads();
  {
    union { u16 s[16]; u32x4 v[2]; } ou;
#pragma unroll
    for (int e = 0; e < 16; e++) ou.s[e] = T[(q * 16 + e) * 72 + rr];
    u16* dst = Vt + ((size_t)bh * 64 + rr) * 2048 + nt * 64 + q * 16;
    *(u32x4*)dst = ou.v[0];
    *(u32x4*)(dst + 8) = ou.v[1];
  }
}

// ---------------------------------------------------------------------------
// flash attention, swapped-QK^T (S^T = mfma(K,Q)): lane owns one q-column.
// Q pre-scaled by 0.125*LOG2E -> softmax in exp2 domain. Sparse bias via
// g-bucketed per-row lists. Defer-max (THR=8). Output bf16 [B*N][512].
// Grid: 1024 flat, XCD-grouped so all 32 q-tiles of one bh share an XCD.
// ---------------------------------------------------------------------------
__global__ __launch_bounds__(256) void attn_kernel(const u16* __restrict__ Qb,
                                                   const u16* __restrict__ Kb,
                                                   const u16* __restrict__ Vt,
                                                   const u32* __restrict__ tpw,
                                                   const u32* __restrict__ tstarts,
                                                   u16* __restrict__ attnout) {
  __shared__ __align__(16) u16 Ks[64 * 64];
  __shared__ __align__(16) u16 Vs[64 * 64];
  __shared__ __align__(16) u16 Ps[4][16 * 64];
  __shared__ u32 pws[64 * 32];
  __shared__ u32 tst[64];

  const int bid = blockIdx.x;
  const int bh = (bid & 7) * 4 + ((bid >> 3) & 3);
  const int qt = bid >> 5;
  const int b = bh >> 3, h = bh & 7;
  const int tid = threadIdx.x, lane = tid & 63, w = tid >> 6;
  const int g = lane >> 4, c = lane & 15;
  const int qbase = qt * 64;

  for (int i = tid; i < 2048; i += 256)
    pws[i] = tpw[((size_t)b * 2048 + qbase) * 32 + i];
  if (tid < 64) tst[tid] = tstarts[b * 2048 + qbase + tid];

  const u16* qptr = Qb + ((size_t)bh * 2048 + qbase + w * 16 + c) * 64 + g * 8;
  u32x4 aq0 = *(const u32x4*)qptr;
  u32x4 aq1 = *(const u32x4*)(qptr + 32);

  float m = -1e30f, ssum = 0.f;
  f32x4 o[4];
#pragma unroll
  for (int db = 0; db < 4; db++) o[db] = f32x4{0.f, 0.f, 0.f, 0.f};

  const int rowl = w * 16 + c;

  const int sr = tid >> 2, sq = tid & 3;
  const u16* ksrc = Kb + ((size_t)bh * 2048 + sr) * 64 + sq * 16;
  const u16* vsrc = Vt + ((size_t)bh * 64 + sr) * 2048 + sq * 16;
  char* ksb = (char*)Ks;
  char* vsb = (char*)Vs;
  char* pwb = (char*)&Ps[w][0];
  const u32 sswz = (u32)((sr & 7) << 4);
  const u32 sb0 = (u32)(sr * 128 + sq * 32);

  // hoisted LDS offsets (rows db*16+c / cb*16+c are the same set)
  u32 koff[4][2], poff2[2], pwoff[4][2];
#pragma unroll
  for (int cb = 0; cb < 4; cb++) {
    int row = cb * 16 + c;
    u32 sz = (u32)((row & 7) << 4);
    koff[cb][0] = ((u32)(row * 128 + g * 16)) ^ sz;
    koff[cb][1] = ((u32)(row * 128 + g * 16 + 64)) ^ sz;
  }
  {
    u32 sz = (u32)((c & 7) << 4);
#pragma unroll
    for (int mm = 0; mm < 2; mm++) poff2[mm] = ((u32)(c * 128 + mm * 64 + g * 16)) ^ sz;
#pragma unroll
    for (int cb = 0; cb < 4; cb++)
#pragma unroll
      for (int hh = 0; hh < 2; hh++)
        pwoff[cb][hh] = ((u32)(c * 128 + cb * 32 + g * 8 + hh * 4)) ^ sz;
  }

  __syncthreads();
  u32 stw = tst[rowl];
  int p = (int)((stw >> (8 * g)) & 255u);
  const int pend = (g == 3) ? 32 : (int)((stw >> (8 * g + 8)) & 255u);

  for (int jt = 0; jt < 2048; jt += 64) {
    __syncthreads();
    {
      u32x4 k0 = *(const u32x4*)(ksrc + (size_t)jt * 64);
      u32x4 k1 = *(const u32x4*)(ksrc + (size_t)jt * 64 + 8);
      u32x4 v0 = *(const u32x4*)(vsrc + jt);
      u32x4 v1 = *(const u32x4*)(vsrc + jt + 8);
      *(u32x4*)(ksb + ((sb0 + 0) ^ sswz)) = k0;
      *(u32x4*)(ksb + ((sb0 + 16) ^ sswz)) = k1;
      *(u32x4*)(vsb + ((sb0 + 0) ^ sswz)) = v0;
      *(u32x4*)(vsb + ((sb0 + 16) ^ sswz)) = v1;
    }
    __syncthreads();

    // S^T = K Q^T: lane holds S[kv=jt+16cb+4g+r][q=rowl]
    f32x4 s[4];
#pragma unroll
    for (int cb = 0; cb < 4; cb++) {
      u32x4 bk0 = *(const u32x4*)(ksb + koff[cb][0]);
      u32x4 bk1 = *(const u32x4*)(ksb + koff[cb][1]);
      f32x4 t = f32x4{0.f, 0.f, 0.f, 0.f};
      mfma_b16(t, bk0, aq0);
      mfma_b16(t, bk1, aq1);
      s[cb] = t;
    }
    mfma_fence();

    // sparse bias (this lane's g-bucket only)
    const int jtend = jt + 64;
    while (p < pend) {
      u32 e = pws[rowl * 32 + p];
      int j = (int)(e >> 16);
      if (j >= jtend) break;
      float wv = __builtin_bit_cast(float, e << 16);
      int rel = j - jt - 4 * g;
#pragma unroll
      for (int cb = 0; cb < 4; cb++)
#pragma unroll
        for (int r = 0; r < 4; r++) s[cb][r] += (rel == cb * 16 + r) ? wv : 0.f;
      p++;
    }

    // online softmax (exp2 domain), defer-max THR=8
    float tm = fmaxf(fmaxf(fmaxf(s[0][0], s[0][1]), fmaxf(s[0][2], s[0][3])),
                     fmaxf(fmaxf(s[1][0], s[1][1]), fmaxf(s[1][2], s[1][3])));
    tm = fmaxf(tm, fmaxf(fmaxf(fmaxf(s[2][0], s[2][1]), fmaxf(s[2][2], s[2][3])),
                         fmaxf(fmaxf(s[3][0], s[3][1]), fmaxf(s[3][2], s[3][3]))));
    tm = fmaxf(tm, __shfl_xor(tm, 16, 64));
    tm = fmaxf(tm, __shfl_xor(tm, 32, 64));
    if (!__all(tm - m <= 8.f)) {
      float mn = fmaxf(m, tm);
      float f = exp2v(m - mn);
      m = mn;
      ssum *= f;
#pragma unroll
      for (int db = 0; db < 4; db++) o[db] *= f;
    }
    float lsum = 0.f;
#pragma unroll
    for (int cb = 0; cb < 4; cb++) {
      float e0 = exp2v(s[cb][0] - m);
      float e1 = exp2v(s[cb][1] - m);
      float e2 = exp2v(s[cb][2] - m);
      float e3 = exp2v(s[cb][3] - m);
      lsum += (e0 + e1) + (e2 + e3);
      *(u32*)(pwb + pwoff[cb][0]) = cvtpk(e0, e1);
      *(u32*)(pwb + pwoff[cb][1]) = cvtpk(e2, e3);
    }
    ssum += lsum;

    // O^T += V^T P : o[db] cols q=c, rows d=db*16+4g+r
    u32x4 pf0 = *(const u32x4*)(pwb + poff2[0]);
    u32x4 pf1 = *(const u32x4*)(pwb + poff2[1]);
#pragma unroll
    for (int db = 0; db < 4; db++) {
      u32x4 bv0 = *(const u32x4*)(vsb + koff[db][0]);
      u32x4 bv1 = *(const u32x4*)(vsb + koff[db][1]);
      mfma_b16(o[db], bv0, pf0);
      mfma_b16(o[db], bv1, pf1);
    }
    mfma_fence();
  }

  ssum += __shfl_xor(ssum, 16, 64);
  ssum += __shfl_xor(ssum, 32, 64);
  float inv = 1.f / ssum;
  const int n = qbase + w * 16 + c;
  u16* obase = attnout + ((size_t)b * 2048 + n) * 512 + h * 64 + 4 * g;
#pragma unroll
  for (int db = 0; db < 4; db++) {
    u32x2 st;
    st[0] = cvtpk(o[db][0] * inv, o[db][1] * inv);
    st[1] = cvtpk(o[db][2] * inv, o[db][3] * inv);
    *(u32x2*)(obase + db * 16) = st;
  }
}

// ---------------------------------------------------------------------------
extern "C" void kernel_launch(void* const* d_in, const int* in_sizes, int n_in,
                              void* d_out, int out_size, void* d_ws, size_t ws_size,
                              hipStream_t stream) {
  (void)in_sizes; (void)n_in; (void)out_size; (void)ws_size;
  const float* x = (const float*)d_in[0];
  const float* sim = (const float*)d_in[1];
  const float* Wq = (const float*)d_in[2];
  const float* bq = (const float*)d_in[3];
  const float* Wk = (const float*)d_in[4];
  const float* bk = (const float*)d_in[5];
  const float* Wv = (const float*)d_in[6];
  const float* bv = (const float*)d_in[7];
  const float* Wo = (const float*)d_in[8];
  const float* bo = (const float*)d_in[9];
  const float* tau = (const float*)d_in[10];
  float* out = (float*)d_out;

  char* ws = (char*)d_ws;
  size_t off = 0;
  auto alloc = [&](size_t bytes) {
    void* p = ws + off;
    off += (bytes + 255) & ~(size_t)255;
    return p;
  };
  u16* xb = (u16*)alloc((size_t)8192 * 256 * 2);
  u16* WqkvT = (u16*)alloc((size_t)1536 * 256 * 2);
  u16* WoT = (u16*)alloc((size_t)512 * 512 * 2);
  float* biasQKV = (float*)alloc((size_t)1536 * 4);
  u16* Qb = (u16*)alloc((size_t)32 * 2048 * 64 * 2);
  u16* Kb = (u16*)alloc((size_t)32 * 2048 * 64 * 2);
  u16* Vb = (u16*)alloc((size_t)32 * 2048 * 64 * 2);
  u16* Vt = (u16*)alloc((size_t)32 * 2048 * 64 * 2);
  u16* attnout = (u16*)alloc((size_t)8192 * 512 * 2);
  u32* tpw = (u32*)alloc((size_t)8192 * 32 * 4);
  u32* tstarts = (u32*)alloc((size_t)8192 * 4);

  prep_kernel<<<dim3(1185), dim3(256), 0, stream>>>(x, Wq, Wk, Wv, Wo, bq, bk, bv, xb, WqkvT,
                                                    WoT, biasQKV);
  topk_kernel<<<dim3(2048), dim3(256), 0, stream>>>(sim, tau, tpw, tstarts);
  gemm_nt<0><<<dim3(12, 64), dim3(256), 0, stream>>>(xb, WqkvT, biasQKV, Qb, Kb, Vb, nullptr,
                                                     8192, 1536, 256);
  transpose_v<<<dim3(32, 32), dim3(256), 0, stream>>>(Vb, Vt);
  attn_kernel<<<dim3(1024), dim3(256), 0, stream>>>(Qb, Kb, Vt, tpw, tstarts, attnout);
  gemm_nt<1><<<dim3(4, 64), dim3(256), 0, stream>>>(attnout, WoT, bo, nullptr, nullptr, nullptr,
                                                    out, 8192, 512, 512);
}